// Round 15
// baseline (44.327 us; speedup 1.0000x reference)
//
#include <hip/hip_runtime.h>

typedef __bf16 bf16x8 __attribute__((ext_vector_type(8)));
typedef float f32x16 __attribute__((ext_vector_type(16)));
typedef int i32x2 __attribute__((ext_vector_type(2)));
typedef unsigned int u32;

#define NCH 8   // 8 chunks of 64 keys = 512-key window

static __device__ __forceinline__ u32 cvt_pk_bf16(float lo, float hi) {
    u32 r;
    asm("v_cvt_pk_bf16_f32 %0, %1, %2" : "=v"(r) : "v"(lo), "v"(hi));
    return r;
}

__global__ __launch_bounds__(512, 4)
void local_attn_kernel(const float* __restrict__ qg, const float* __restrict__ kg,
                       const float* __restrict__ vg, float* __restrict__ og)
{
    // K: [buf][key][dim], 16B-slot swizzle (slot ^= key&7) -> conflict-free b128 r/w
    __shared__ __align__(16) __bf16 sK[2][64][64];
    // V (this block's 32-dim half): [buf][ldim][keypair] u32; col = 4*sl + j,
    // sl = kq ^ (ldim&7) ^ ((ldim>>2)&7)  (r7-validated swizzle)
    __shared__ __align__(16) u32 sVp[2][32][32];

    // XCD swizzle (bijective, 1024 = 8*128): both dhalf-blocks of a bucket + neighbor
    // buckets (sharing K/V) land on the same XCD
    const int bid = ((blockIdx.x & 7) << 7) | (blockIdx.x >> 3);
    const int bh = bid >> 5, bi = (bid >> 1) & 15, dh = bid & 1;  // dh: output dim half
    const int tid = threadIdx.x, w = tid >> 6;
    const int lane = tid & 63, l31 = lane & 31, h = lane >> 5;

    const long long base = (long long)bh << 18;           // *4096*64
    const float* qp = qg + base + ((long long)bi << 14);  // *256*64
    const float* kp = kg + base + (((long long)(bi - 1)) << 14);
    const float* vp = vg + base + (((long long)(bi - 1)) << 14);
    float*       op = og + base + ((long long)bi << 14);

    // ---- Q B-frags (full dim; needed for S), pre-scaled by 0.125*log2(e)
    bf16x8 qf[4];
    {
        const float QS = 0.18033688011112042f;   // (1/8)*log2(e): exp(s/8)=2^(s*QS)
        const float* qrow = qp + (w * 32 + l31) * 64 + 8 * h;
#pragma unroll
        for (int ks = 0; ks < 4; ++ks) {
            float4 f0 = *(const float4*)(qrow + ks * 16);
            float4 f1 = *(const float4*)(qrow + ks * 16 + 4);
            bf16x8 t;
            t[0] = (__bf16)(f0.x * QS); t[1] = (__bf16)(f0.y * QS);
            t[2] = (__bf16)(f0.z * QS); t[3] = (__bf16)(f0.w * QS);
            t[4] = (__bf16)(f1.x * QS); t[5] = (__bf16)(f1.y * QS);
            t[6] = (__bf16)(f1.z * QS); t[7] = (__bf16)(f1.w * QS);
            qf[ks] = t;
        }
    }

    f32x16 o0;                          // 32 queries x 32 dims (this block's half)
#pragma unroll
    for (int i = 0; i < 16; ++i) o0[i] = 0.f;
    float lsum = 0.f;                   // full row-sum (computed redundantly per dh)

    // staging maps. K: all 512 threads (full chunk). V: threads 0..255 (half-dim chunk).
    const int skey = tid >> 3, stg = tid & 7;              // K: key, 8-float group
    const int kslot = (stg ^ (skey & 7)) << 3;
    const int vkp = (tid & 255) >> 3;                      // V keypair 0..31
    const int vd0 = (tid & 7) * 4;                         // V local dim 0..28
    const int vkq = vkp >> 2, vj = vkp & 3;
    const int x0 = ((vd0 + 0) & 7) ^ (((vd0 + 0) >> 2) & 7);
    const int x1 = ((vd0 + 1) & 7) ^ (((vd0 + 1) >> 2) & 7);
    const int x2 = ((vd0 + 2) & 7) ^ (((vd0 + 2) >> 2) & 7);
    const int x3 = ((vd0 + 3) & 7) ^ (((vd0 + 3) >> 2) & 7);
    const float* kA = kp + skey * 64 + stg * 8;
    const float* vA = vp + (2 * vkp) * 64 + dh * 32 + vd0;
    const bool vactive = (tid < 256);   // wave-uniform (waves 0-3)

    const int c0 = (bi == 0) ? 4 : 0;      // bucket 0: first 256 window keys are pad
    const int qpos = w * 32 + l31;
    const int wlim = 32 * w + 287;

    int cur = 0;
    // T14 staging registers: live only within one barrier interval
    float4 k0r, k1r, v0r, v1r;

#define STAGE_LOAD(c) do {                                   \
        const float* ks_ = kA + (c) * (64 * 64);             \
        k0r = *(const float4*)ks_;                           \
        k1r = *(const float4*)(ks_ + 4);                     \
        if (vactive) {                                       \
            const float* vs_ = vA + (c) * (64 * 64);         \
            v0r = *(const float4*)vs_;                       \
            v1r = *(const float4*)(vs_ + 64);                \
        }                                                    \
    } while (0)

#define STAGE_WRITE(buf) do {                                                     \
        union { u32 u[4]; bf16x8 b; } kv_;                                        \
        kv_.u[0] = cvt_pk_bf16(k0r.x, k0r.y);                                     \
        kv_.u[1] = cvt_pk_bf16(k0r.z, k0r.w);                                     \
        kv_.u[2] = cvt_pk_bf16(k1r.x, k1r.y);                                     \
        kv_.u[3] = cvt_pk_bf16(k1r.z, k1r.w);                                     \
        *(bf16x8*)&sK[buf][skey][kslot] = kv_.b;                                  \
        if (vactive) {                                                            \
            sVp[buf][vd0 + 0][((vkq ^ x0) << 2) + vj] = cvt_pk_bf16(v0r.x, v1r.x);\
            sVp[buf][vd0 + 1][((vkq ^ x1) << 2) + vj] = cvt_pk_bf16(v0r.y, v1r.y);\
            sVp[buf][vd0 + 2][((vkq ^ x2) << 2) + vj] = cvt_pk_bf16(v0r.z, v1r.z);\
            sVp[buf][vd0 + 3][((vkq ^ x3) << 2) + vj] = cvt_pk_bf16(v0r.w, v1r.w);\
        }                                                                         \
    } while (0)

    STAGE_LOAD(c0);
    STAGE_WRITE(0);

    for (int c = c0; c < NCH; ++c) {
        __syncthreads();                       // buf `cur` ready for all waves
        const bool pf = (c + 1 < NCH);         // block-uniform
        if (pf) STAGE_LOAD(c + 1);             // issue early: latency hides under compute

        const int kbase = c * 64;
#pragma unroll
        for (int kt = 0; kt < 2; ++kt) {
            const int kb0 = kbase + 32 * kt;
            if (kb0 > wlim) continue;          // wave-uniform causal skip

            // ---- QK^T swapped: S[key][query] = mfma(K_A, Q_B) ----
            const int key = kt * 32 + l31;
            const int ksw = key & 7;
            bf16x8 kfa[4];
#pragma unroll
            for (int ks = 0; ks < 4; ++ks)
                kfa[ks] = *(const bf16x8*)&sK[cur][key][((ks * 2 + h) ^ ksw) << 3];
            f32x16 s;
#pragma unroll
            for (int i2 = 0; i2 < 16; ++i2) s[i2] = 0.f;
#pragma unroll
            for (int ks = 0; ks < 4; ++ks)
                s = __builtin_amdgcn_mfma_f32_32x32x16_bf16(kfa[ks], qf[ks], s, 0, 0, 0);

            // ---- exp2 fused into bf16 pack (scores bounded; no max-tracking) ----
            u32 wds[8];
            if (kb0 + 31 <= 32 * w + 256) {    // fully unmasked for this wave
#pragma unroll
                for (int m = 0; m < 8; ++m) {
                    const float e0 = __builtin_amdgcn_exp2f(s[2 * m]);
                    const float e1 = __builtin_amdgcn_exp2f(s[2 * m + 1]);
                    lsum += e0 + e1;
                    wds[m] = cvt_pk_bf16(e0, e1);
                }
            } else {
                const int jb = kb0 + 4 * h;
#pragma unroll
                for (int m = 0; m < 8; ++m) {
                    const int r0 = 2 * m, r1 = 2 * m + 1;
                    const int j0 = jb + (r0 & 3) + 8 * (r0 >> 2);
                    const int j1 = jb + (r1 & 3) + 8 * (r1 >> 2);
                    float e0 = __builtin_amdgcn_exp2f(s[r0]);
                    float e1 = __builtin_amdgcn_exp2f(s[r1]);
                    e0 = (j0 > qpos + 256) ? 0.f : e0;
                    e1 = (j1 > qpos + 256) ? 0.f : e1;
                    lsum += e0 + e1;
                    wds[m] = cvt_pk_bf16(e0, e1);
                }
            }

            // ---- P -> bf16 A-frags in-register (permlane32_swap); PV on half-dim ----
#pragma unroll
            for (int kis = 0; kis < 2; ++kis) {
                i32x2 r02 = __builtin_amdgcn_permlane32_swap(
                    (int)wds[4 * kis + 0], (int)wds[4 * kis + 2], false, false);
                i32x2 r13 = __builtin_amdgcn_permlane32_swap(
                    (int)wds[4 * kis + 1], (int)wds[4 * kis + 3], false, false);
                union { u32 u[4]; bf16x8 b; } pu;
                pu.u[0] = (u32)r02.x; pu.u[1] = (u32)r13.x;
                pu.u[2] = (u32)r02.y; pu.u[3] = (u32)r13.y;

                const int G = (kt * 2 + kis) * 2 + h;             // key-group 0..7
                const int sl = G ^ (l31 & 7) ^ ((l31 >> 2) & 7);
                bf16x8 vb = *(const bf16x8*)&sVp[cur][l31][sl << 2];
                o0 = __builtin_amdgcn_mfma_f32_32x32x16_bf16(pu.b, vb, o0, 0, 0, 0);
            }
        }

        if (pf) STAGE_WRITE(cur ^ 1);          // write late: after compute, before barrier
        cur ^= 1;
    }

    // ---- epilogue: combine half-sums, broadcast per-query inv, store half-dim ----
    lsum += __shfl_xor(lsum, 32, 64);
    const float inv = 1.0f / lsum;     // valid at lane l31 for query w*32+l31
#pragma unroll
    for (int r = 0; r < 16; ++r) {
        const int qr = (r & 3) + 8 * (r >> 2) + 4 * h;   // query row of C reg r
        const float iq = __shfl(inv, qr, 64);
        op[(long long)(w * 32 + qr) * 64 + dh * 32 + l31] = o0[r] * iq;
    }
}

extern "C" void kernel_launch(void* const* d_in, const int* in_sizes, int n_in,
                              void* d_out, int out_size, void* d_ws, size_t ws_size,
                              hipStream_t stream) {
    const float* q = (const float*)d_in[0];
    const float* k = (const float*)d_in[1];
    const float* v = (const float*)d_in[2];
    float* out = (float*)d_out;
    // 32 bh * 16 buckets * 2 dim-halves = 1024 blocks, 512 threads (8 waves)
    local_attn_kernel<<<dim3(1024), dim3(512), 0, stream>>>(q, k, v, out);
}